// Round 1
// baseline (2266.872 us; speedup 1.0000x reference)
//
#include <hip/hip_runtime.h>
#include <float.h>
#include <limits.h>

// Problem constants (fixed by setup_inputs)
static const int BG    = 256;    // graphs
static const int SORTN = 1024;   // bitonic size >= MAXN=1000
static const int DF    = 193;    // 64+64+64+1
static const int K2C   = 27;
static const int K1C   = 3;
static const int NRESC = 973;    // MAXN - K2
static const int PLEN  = 5790;   // 30*193

#define DEV static __device__ __forceinline__

DEV float warp_sum64(float v){
#pragma unroll
  for (int o = 1; o < 64; o <<= 1) v += __shfl_xor(v, o);
  return v;
}
DEV float warp_min64(float v){
#pragma unroll
  for (int o = 1; o < 64; o <<= 1) v = fminf(v, __shfl_xor(v, o));
  return v;
}
DEV float feat_at(const float* __restrict__ x1, const float* __restrict__ x2,
                  const float* __restrict__ x3, const float* __restrict__ x4,
                  int node, int d){
  if (d < 64)  return x1[node*64 + d];
  if (d < 128) return x2[node*64 + (d-64)];
  if (d < 192) return x3[node*64 + (d-128)];
  return x4[node];
}

// ---------------- graph prep ----------------
__global__ __launch_bounds__(256) void k_count(const int* __restrict__ cols, int* __restrict__ cnt, int E){
  int e = blockIdx.x*256 + threadIdx.x;
  if (e < E) atomicAdd(&cnt[cols[e]], 1);
}
__global__ __launch_bounds__(256) void k_count_graph(const int* __restrict__ batch, int* __restrict__ gcount, int NT){
  int i = blockIdx.x*256 + threadIdx.x;
  if (i < NT) atomicAdd(&gcount[batch[i]], 1);
}
__global__ void k_scan_graph(const int* __restrict__ gcount, int* __restrict__ goff){
  if (threadIdx.x == 0){
    int run = 0;
    for (int g = 0; g < BG; g++){ goff[g] = run; run += gcount[g]; }
    goff[BG] = run;
  }
}
__global__ __launch_bounds__(256) void k_dis(const int* __restrict__ cnt, float* __restrict__ dis, int NT){
  int i = blockIdx.x*256 + threadIdx.x;
  if (i < NT) dis[i] = 1.0f / sqrtf((float)cnt[i] + 1.0f);
}
__global__ __launch_bounds__(256) void k_scan1(const int* __restrict__ cnt, int* __restrict__ bsum, int NT){
  __shared__ int sm[256];
  int base = blockIdx.x * 1024;
  int s = 0;
  for (int i = threadIdx.x; i < 1024; i += 256){
    int g = base + i;
    s += (g < NT) ? cnt[g] : 0;
  }
  sm[threadIdx.x] = s; __syncthreads();
  for (int o = 128; o > 0; o >>= 1){
    if (threadIdx.x < o) sm[threadIdx.x] += sm[threadIdx.x + o];
    __syncthreads();
  }
  if (threadIdx.x == 0) bsum[blockIdx.x] = sm[0];
}
__global__ void k_scan2(const int* __restrict__ bsum, int* __restrict__ boff, int nb, int* __restrict__ csr_off, int NT){
  if (threadIdx.x == 0){
    int run = 0;
    for (int b = 0; b < nb; b++){ boff[b] = run; run += bsum[b]; }
    csr_off[NT] = run;
  }
}
__global__ __launch_bounds__(256) void k_scan3(const int* __restrict__ cnt, const int* __restrict__ boff,
                                               int* __restrict__ csr_off, int NT){
  __shared__ int sm[256];
  int base = blockIdx.x * 1024, tid = threadIdx.x;
  int v[4]; int s = 0;
#pragma unroll
  for (int q = 0; q < 4; q++){
    int g = base + tid*4 + q;
    v[q] = (g < NT) ? cnt[g] : 0;
    s += v[q];
  }
  sm[tid] = s; __syncthreads();
  for (int o = 1; o < 256; o <<= 1){
    int add = (tid >= o) ? sm[tid - o] : 0;
    __syncthreads();
    sm[tid] += add;
    __syncthreads();
  }
  int excl = boff[blockIdx.x] + ((tid > 0) ? sm[tid - 1] : 0);
#pragma unroll
  for (int q = 0; q < 4; q++){
    int g = base + tid*4 + q;
    if (g < NT) csr_off[g] = excl;
    excl += v[q];
  }
}
__global__ __launch_bounds__(256) void k_fill(const int* __restrict__ rows, const int* __restrict__ cols,
                                              const float* __restrict__ dis, int* __restrict__ cursor,
                                              int* __restrict__ csr_src, float* __restrict__ csr_w, int E){
  int e = blockIdx.x*256 + threadIdx.x;
  if (e >= E) return;
  int r = rows[e], c = cols[e];
  int pos = atomicAdd(&cursor[c], 1);
  csr_src[pos] = r;
  csr_w[pos]   = dis[r] * dis[c];
}
// canonicalize adjacency order -> deterministic fp accumulation
__global__ __launch_bounds__(256) void k_sortadj(const int* __restrict__ off, int* __restrict__ srcs,
                                                 float* __restrict__ ws, int NT){
  int v = blockIdx.x*256 + threadIdx.x;
  if (v >= NT) return;
  int s0 = off[v], s1 = off[v+1];
  for (int i = s0 + 1; i < s1; i++){
    int ks = srcs[i]; float kw = ws[i];
    int j = i - 1;
    while (j >= s0 && srcs[j] > ks){ srcs[j+1] = srcs[j]; ws[j+1] = ws[j]; j--; }
    srcs[j+1] = ks; ws[j+1] = kw;
  }
}

// ---------------- GCN layers ----------------
template<int K>
__global__ __launch_bounds__(256) void k_gemm(const float* __restrict__ X, const float* __restrict__ W,
                                              float* __restrict__ H, int NT){
  __shared__ float wL[K*64];
  __shared__ float xL[32*K];
  int tid = threadIdx.x;
  for (int i = tid; i < K*64; i += 256) wL[i] = W[i];
  int rbase = blockIdx.x * 32;
  for (int i = tid; i < 32*K; i += 256){
    int r = i / K, cc = i % K;
    int gr = rbase + r;
    xL[i] = (gr < NT) ? X[(size_t)gr*K + cc] : 0.f;
  }
  __syncthreads();
  int c = tid & 63, r0 = tid >> 6;
  float acc[8];
#pragma unroll
  for (int m = 0; m < 8; m++) acc[m] = 0.f;
  for (int k = 0; k < K; k++){
    float w = wL[k*64 + c];
#pragma unroll
    for (int m = 0; m < 8; m++) acc[m] = fmaf(xL[(r0 + 4*m)*K + k], w, acc[m]);
  }
#pragma unroll
  for (int m = 0; m < 8; m++){
    int gr = rbase + r0 + 4*m;
    if (gr < NT) H[(size_t)gr*64 + c] = acc[m];
  }
}

template<bool FUSE_DOT>
__global__ __launch_bounds__(256) void k_agg(const float* __restrict__ H, const int* __restrict__ off,
                                             const int* __restrict__ srcs, const float* __restrict__ ws,
                                             const float* __restrict__ dis, const float* __restrict__ bias,
                                             const float* __restrict__ W4, float* __restrict__ Xout,
                                             float* __restrict__ H4, int NT){
  int wid  = blockIdx.x*4 + (threadIdx.x >> 6);
  int lane = threadIdx.x & 63;
  if (wid >= NT) return;
  int s0 = off[wid], s1 = off[wid+1];
  float acc = 0.f;
  for (int e = s0; e < s1; e++){
    int s  = srcs[e];
    float w = ws[e];
    acc = fmaf(w, H[(size_t)s*64 + lane], acc);
  }
  float dv = dis[wid];
  float out = acc + dv*dv*H[(size_t)wid*64 + lane] + bias[lane];
  float t = tanhf(out);
  Xout[(size_t)wid*64 + lane] = t;
  if (FUSE_DOT){
    float p = warp_sum64(t * W4[lane]);
    if (lane == 0) H4[wid] = p;
  }
}

__global__ __launch_bounds__(256) void k_agg1(const float* __restrict__ H4, const int* __restrict__ off,
                                              const int* __restrict__ srcs, const float* __restrict__ ws,
                                              const float* __restrict__ dis, const float* __restrict__ b4,
                                              float* __restrict__ x4, int NT){
  int v = blockIdx.x*256 + threadIdx.x;
  if (v >= NT) return;
  int s0 = off[v], s1 = off[v+1];
  float acc = 0.f;
  for (int e = s0; e < s1; e++) acc = fmaf(ws[e], H4[srcs[e]], acc);
  float dv = dis[v];
  x4[v] = tanhf(acc + dv*dv*H4[v] + b4[0]);
}

// ---------------- global min (fill value) ----------------
__global__ __launch_bounds__(256) void k_min(const float* __restrict__ x1, const float* __restrict__ x2,
                                             const float* __restrict__ x3, const float* __restrict__ x4,
                                             int NT, float* __restrict__ bmin){
  int stride = gridDim.x * 256;
  int tid = blockIdx.x*256 + threadIdx.x;
  float mn = FLT_MAX;
  int total4 = NT * 16;  // NT*64/4
  for (int i = tid; i < total4; i += stride){
    float4 a = ((const float4*)x1)[i];
    float4 b = ((const float4*)x2)[i];
    float4 c = ((const float4*)x3)[i];
    mn = fminf(mn, fminf(fminf(a.x,a.y), fminf(a.z,a.w)));
    mn = fminf(mn, fminf(fminf(b.x,b.y), fminf(b.z,b.w)));
    mn = fminf(mn, fminf(fminf(c.x,c.y), fminf(c.z,c.w)));
  }
  for (int i = tid; i < NT; i += stride) mn = fminf(mn, x4[i]);
  mn = warp_min64(mn);
  __shared__ float wm[4];
  if ((threadIdx.x & 63) == 0) wm[threadIdx.x >> 6] = mn;
  __syncthreads();
  if (threadIdx.x == 0)
    bmin[blockIdx.x] = fminf(fminf(wm[0], wm[1]), fminf(wm[2], wm[3]));
}
__global__ __launch_bounds__(256) void k_min2(const float* __restrict__ bmin, int nb, float* __restrict__ minv){
  __shared__ float sm[256];
  float m = FLT_MAX;
  for (int i = threadIdx.x; i < nb; i += 256) m = fminf(m, bmin[i]);
  sm[threadIdx.x] = m; __syncthreads();
  for (int o = 128; o > 0; o >>= 1){
    if (threadIdx.x < o) sm[threadIdx.x] = fminf(sm[threadIdx.x], sm[threadIdx.x + o]);
    __syncthreads();
  }
  if (threadIdx.x == 0) minv[0] = sm[0];
}

// ---------------- SortPool + sim top-k ----------------
__global__ __launch_bounds__(256) void k_sortpool(const float* __restrict__ x1, const float* __restrict__ x2,
                                                  const float* __restrict__ x3, const float* __restrict__ x4,
                                                  const int* __restrict__ gcount, const int* __restrict__ goff,
                                                  const float* __restrict__ minv, float* __restrict__ pooled){
  __shared__ float sval[SORTN];
  __shared__ int   sidx[SORTN];
  __shared__ float sq[NRESC + 3];
  __shared__ float Srow[DF];
  __shared__ float sTsum;
  __shared__ float wtv[12];
  __shared__ int   wti[12];
  __shared__ float ftv[3];
  __shared__ int   fti[3];

  int g = blockIdx.x, tid = threadIdx.x;
  int n = gcount[g], base = goff[g];
  float fill = minv[0] - 1.0f;
  int nv = (n < NRESC) ? n : NRESC;
  int nreal = n - K2C;  // res rows below this are real
  float nf = (float)nv;

  // load sort keys
  for (int i = tid; i < SORTN; i += 256){
    sval[i] = (i < n) ? x4[base + i] : -FLT_MAX;
    sidx[i] = i;
  }
  __syncthreads();

  // bitonic sort: order = (val desc, idx asc)  == stable argsort(-val)
  for (int k = 2; k <= SORTN; k <<= 1){
    for (int j = k >> 1; j > 0; j >>= 1){
      for (int t = tid; t < SORTN/2; t += 256){
        int i   = 2*t - (t & (j - 1));
        int ixj = i | j;
        bool up = ((i & k) == 0);
        float va = sval[i], vb = sval[ixj];
        int   ia = sidx[i], ib = sidx[ixj];
        bool aBeforeB = (va > vb) || (va == vb && ia < ib);
        bool bBeforeA = (vb > va) || (vb == va && ib < ia);
        bool doswap = up ? bBeforeA : aBeforeB;
        if (doswap){ sval[i] = vb; sval[ixj] = va; sidx[i] = ib; sidx[ixj] = ia; }
      }
      __syncthreads();
    }
  }

  // x_sort: first K2 rows, fill -> 0
  for (int i = tid; i < K2C*DF; i += 256){
    int r = i / DF, d = i - r*DF;
    float v = (r < n) ? feat_at(x1, x2, x3, x4, base + sidx[r], d) : 0.f;
    pooled[(size_t)g*PLEN + i] = v;
  }

  int wid = tid >> 6, lane = tid & 63;

  // Phase A1: sq per res row (wave per row)
  for (int j = wid; j < NRESC; j += 4){
    if (j < nv){
      float a, b, c, d192;
      if (j < nreal){
        int node = base + sidx[K2C + j];
        a = x1[node*64 + lane]; b = x2[node*64 + lane]; c = x3[node*64 + lane];
        d192 = x4[node];
      } else { a = fill; b = fill; c = fill; d192 = fill; }
      float p = warp_sum64(a*a + b*b + c*c);
      if (lane == 0) sq[j] = p + d192*d192;
    }
  }

  // Phase A2: Srow (thread per channel, coalesced across d)
  if (tid < DF){
    float s = 0.f;
    for (int j = 0; j < nv; j++){
      float v;
      if (j < nreal) v = feat_at(x1, x2, x3, x4, base + sidx[K2C + j], tid);
      else v = fill;
      s += v;
    }
    Srow[tid] = s;
  }
  __syncthreads();

  // Tsum (constant offset across rows; order irrelevant for ranking)
  if (tid == 0){
    float s = 0.f;
    for (int j = 0; j < nv; j++) s += sq[j];
    sTsum = s;
  }
  __syncthreads();

  // Phase B: sim + per-wave top3 (val desc, idx asc)
  float tv0 = -FLT_MAX, tv1 = -FLT_MAX, tv2 = -FLT_MAX;
  int   ti0 = INT_MAX,  ti1 = INT_MAX,  ti2 = INT_MAX;
  for (int j = wid; j < NRESC; j += 4){
    if (j >= nv) continue;
    float a, b, c, d192;
    if (j < nreal){
      int node = base + sidx[K2C + j];
      a = x1[node*64 + lane]; b = x2[node*64 + lane]; c = x3[node*64 + lane];
      d192 = x4[node];
    } else { a = fill; b = fill; c = fill; d192 = fill; }
    float p = warp_sum64(a*Srow[lane] + b*Srow[64 + lane] + c*Srow[128 + lane]);
    float dot = p + d192*Srow[192];
    float sim = nf*sq[j] + sTsum - 2.0f*dot;
    if (sim > tv0 || (sim == tv0 && j < ti0)){
      tv2 = tv1; ti2 = ti1; tv1 = tv0; ti1 = ti0; tv0 = sim; ti0 = j;
    } else if (sim > tv1 || (sim == tv1 && j < ti1)){
      tv2 = tv1; ti2 = ti1; tv1 = sim; ti1 = j;
    } else if (sim > tv2 || (sim == tv2 && j < ti2)){
      tv2 = sim; ti2 = j;
    }
  }
  if (lane == 0){
    wtv[wid*3 + 0] = tv0; wti[wid*3 + 0] = ti0;
    wtv[wid*3 + 1] = tv1; wti[wid*3 + 1] = ti1;
    wtv[wid*3 + 2] = tv2; wti[wid*3 + 2] = ti2;
  }
  __syncthreads();
  if (tid == 0){
    float v0 = -FLT_MAX, v1 = -FLT_MAX, v2 = -FLT_MAX;
    int   i0 = INT_MAX,  i1 = INT_MAX,  i2 = INT_MAX;
    for (int q = 0; q < 12; q++){
      float v = wtv[q]; int jj = wti[q];
      if (v > v0 || (v == v0 && jj < i0)){
        v2 = v1; i2 = i1; v1 = v0; i1 = i0; v0 = v; i0 = jj;
      } else if (v > v1 || (v == v1 && jj < i1)){
        v2 = v1; i2 = i1; v1 = v; i1 = jj;
      } else if (v > v2 || (v == v2 && jj < i2)){
        v2 = v; i2 = jj;
      }
    }
    ftv[0] = v0; fti[0] = i0; ftv[1] = v1; fti[1] = i1; ftv[2] = v2; fti[2] = i2;
  }
  __syncthreads();

  // x_simi: gather top-3 res rows (fill rows kept raw)
  for (int i = tid; i < K1C*DF; i += 256){
    int m = i / DF, d = i - m*DF;
    int j = fti[m];
    float v = (j < nreal) ? feat_at(x1, x2, x3, x4, base + sidx[K2C + j], d) : fill;
    pooled[(size_t)g*PLEN + K2C*DF + i] = v;
  }
}

// ---------------- conv5 + pairmax + conv6 ----------------
__global__ __launch_bounds__(256) void k_head(const float* __restrict__ pooled, const float* __restrict__ w5,
                                              const float* __restrict__ b5, const float* __restrict__ w6,
                                              const float* __restrict__ b6, float* __restrict__ h6){
  __shared__ float pl[PLEN];
  __shared__ float h5[30*64];
  __shared__ float mx[15*64];
  int g = blockIdx.x, tid = threadIdx.x;
  for (int i = tid; i < PLEN; i += 256) pl[i] = pooled[(size_t)g*PLEN + i];
  __syncthreads();
  int o = tid & 63, tg = tid >> 6;
  for (int t = tg; t < 30; t += 4){
    float acc = b5[o];
    for (int d = 0; d < DF; d++) acc = fmaf(pl[t*DF + d], w5[o*DF + d], acc);
    h5[t*64 + o] = fmaxf(acc, 0.f);
  }
  __syncthreads();
  for (int i = tid; i < 15*64; i += 256){
    int p = i >> 6, oo = i & 63;
    mx[i] = fmaxf(h5[(2*p)*64 + oo], h5[(2*p + 1)*64 + oo]);
  }
  __syncthreads();
  for (int i = tid; i < 704; i += 256){
    int t = i >> 6, oo = i & 63;
    float acc = b6[oo];
    for (int ii = 0; ii < 64; ii++){
#pragma unroll
      for (int k = 0; k < 5; k++)
        acc = fmaf(mx[(t + k)*64 + ii], w6[(oo*64 + ii)*5 + k], acc);
    }
    h6[(size_t)g*704 + oo*11 + t] = fmaxf(acc, 0.f);  // o-major flatten
  }
}

// ---------------- FC: 256 x 704 @ 704 x 1600, ReLU ----------------
__global__ __launch_bounds__(256) void k_fc(const float* __restrict__ h6, const float* __restrict__ fw,
                                            const float* __restrict__ fb, float* __restrict__ out){
  __shared__ float hL[64*64];
  int tid = threadIdx.x;
  int jb = blockIdx.x*64, bb = blockIdx.y*64;
  int j = jb + (tid & 63);
  int r0 = tid >> 6;
  float acc[16];
#pragma unroll
  for (int m = 0; m < 16; m++) acc[m] = 0.f;
  for (int kk = 0; kk < 704; kk += 64){
    __syncthreads();
    for (int i = tid; i < 64*64; i += 256){
      int r = i >> 6, c = i & 63;
      hL[i] = h6[(size_t)(bb + r)*704 + kk + c];
    }
    __syncthreads();
    for (int k = 0; k < 64; k++){
      float w = fw[(size_t)(kk + k)*1600 + j];
#pragma unroll
      for (int m = 0; m < 16; m++) acc[m] = fmaf(hL[(r0 + 4*m)*64 + k], w, acc[m]);
    }
  }
#pragma unroll
  for (int m = 0; m < 16; m++){
    int b = bb + r0 + 4*m;
    out[(size_t)b*1600 + j] = fmaxf(acc[m] + fb[j], 0.f);
  }
}

extern "C" void kernel_launch(void* const* d_in, const int* in_sizes, int n_in,
                              void* d_out, int out_size, void* d_ws, size_t ws_size,
                              hipStream_t stream){
  const float* x    = (const float*)d_in[0];
  const int*   ei   = (const int*)d_in[1];
  const int*   batch= (const int*)d_in[2];
  const float* W1 = (const float*)d_in[3];  const float* b1 = (const float*)d_in[4];
  const float* W2 = (const float*)d_in[5];  const float* b2 = (const float*)d_in[6];
  const float* W3 = (const float*)d_in[7];  const float* b3 = (const float*)d_in[8];
  const float* W4 = (const float*)d_in[9];  const float* b4 = (const float*)d_in[10];
  const float* w5 = (const float*)d_in[11]; const float* b5 = (const float*)d_in[12];
  const float* w6 = (const float*)d_in[13]; const float* b6 = (const float*)d_in[14];
  const float* fw = (const float*)d_in[15]; const float* fb = (const float*)d_in[16];
  float* out = (float*)d_out;

  const int NT = in_sizes[2];
  const int E  = in_sizes[1] / 2;
  const int* rows = ei;
  const int* cols = ei + E;

  char* ws = (char*)d_ws;
  size_t off = 0;
  auto alloc = [&](size_t bytes) -> char* {
    off = (off + 255) & ~(size_t)255;
    char* p = ws + off;
    off += bytes;
    return p;
  };
  int*   cnt     = (int*)  alloc((size_t)NT * 4);
  int*   gcount  = (int*)  alloc(BG * 4);
  int*   goff    = (int*)  alloc((BG + 1) * 4);
  int*   bsum    = (int*)  alloc(256 * 4);
  int*   boff    = (int*)  alloc(256 * 4);
  float* minv    = (float*)alloc(4);
  float* bmin    = (float*)alloc(2048 * 4);
  float* dis     = (float*)alloc((size_t)NT * 4);
  int*   csr_off = (int*)  alloc((size_t)(NT + 1) * 4);
  int*   cursor  = (int*)  alloc((size_t)NT * 4);
  int*   csr_src = (int*)  alloc((size_t)E * 4);
  float* csr_w   = (float*)alloc((size_t)E * 4);
  float* Hbuf    = (float*)alloc((size_t)NT * 64 * 4);
  float* x1      = (float*)alloc((size_t)NT * 64 * 4);
  float* x2      = (float*)alloc((size_t)NT * 64 * 4);
  float* x3      = (float*)alloc((size_t)NT * 64 * 4);
  float* x4      = (float*)alloc((size_t)NT * 4);
  float* H4      = (float*)alloc((size_t)NT * 4);
  float* pooled  = (float*)alloc((size_t)BG * PLEN * 4);
  float* h6      = (float*)alloc((size_t)BG * 704 * 4);

  const int gridE  = (E + 255) / 256;
  const int gridNT = (NT + 255) / 256;
  const int nbScan = (NT + 1023) / 1024;

  hipMemsetAsync(cnt, 0, (size_t)NT * 4, stream);
  hipMemsetAsync(gcount, 0, BG * 4, stream);

  k_count<<<gridE, 256, 0, stream>>>(cols, cnt, E);
  k_count_graph<<<gridNT, 256, 0, stream>>>(batch, gcount, NT);
  k_scan_graph<<<1, 64, 0, stream>>>(gcount, goff);
  k_dis<<<gridNT, 256, 0, stream>>>(cnt, dis, NT);

  k_scan1<<<nbScan, 256, 0, stream>>>(cnt, bsum, NT);
  k_scan2<<<1, 64, 0, stream>>>(bsum, boff, nbScan, csr_off, NT);
  k_scan3<<<nbScan, 256, 0, stream>>>(cnt, boff, csr_off, NT);
  hipMemcpyAsync(cursor, csr_off, (size_t)NT * 4, hipMemcpyDeviceToDevice, stream);
  k_fill<<<gridE, 256, 0, stream>>>(rows, cols, dis, cursor, csr_src, csr_w, E);
  k_sortadj<<<gridNT, 256, 0, stream>>>(csr_off, csr_src, csr_w, NT);

  const int gridG = (NT + 31) / 32;
  const int gridA = (NT + 3) / 4;

  k_gemm<128><<<gridG, 256, 0, stream>>>(x, W1, Hbuf, NT);
  k_agg<false><<<gridA, 256, 0, stream>>>(Hbuf, csr_off, csr_src, csr_w, dis, b1, W4, x1, H4, NT);
  k_gemm<64><<<gridG, 256, 0, stream>>>(x1, W2, Hbuf, NT);
  k_agg<false><<<gridA, 256, 0, stream>>>(Hbuf, csr_off, csr_src, csr_w, dis, b2, W4, x2, H4, NT);
  k_gemm<64><<<gridG, 256, 0, stream>>>(x2, W3, Hbuf, NT);
  k_agg<true><<<gridA, 256, 0, stream>>>(Hbuf, csr_off, csr_src, csr_w, dis, b3, W4, x3, H4, NT);
  k_agg1<<<gridNT, 256, 0, stream>>>(H4, csr_off, csr_src, csr_w, dis, b4, x4, NT);

  k_min<<<2048, 256, 0, stream>>>(x1, x2, x3, x4, NT, bmin);
  k_min2<<<1, 256, 0, stream>>>(bmin, 2048, minv);

  k_sortpool<<<BG, 256, 0, stream>>>(x1, x2, x3, x4, gcount, goff, minv, pooled);
  k_head<<<BG, 256, 0, stream>>>(pooled, w5, b5, w6, b6, h6);
  k_fc<<<dim3(25, 4), 256, 0, stream>>>(h6, fw, fb, out);
}